// Round 1
// 283.151 us; speedup vs baseline: 1.0462x; 1.0462x over previous
//
#include <hip/hip_runtime.h>
#include <stdint.h>

typedef unsigned short u16;
typedef unsigned int   u32;
typedef short bf16x8 __attribute__((ext_vector_type(8)));   // 8 bf16 in 4 VGPRs
typedef u16   u16x8  __attribute__((ext_vector_type(8)));
typedef u16   u16x4  __attribute__((ext_vector_type(4)));
typedef float f32x4  __attribute__((ext_vector_type(4)));

#define B_   2
#define S_   2048
#define HQ_  32
#define HKV_ 8
#define D_   128
#define SCALE 0.08838834764831845f   // 1/sqrt(128), fixed by problem shape

// workspace (bf16 elems, 16.8 MB): Kr [B][HKV][S][D] roped K; Vt [B][HKV][D][S]
#define KR_ELEMS (B_*HKV_*S_*D_)

// rope_pre grid: K-rope blocks (4 d-pairs per thread) + V-transpose blocks (LDS tile)
#define KT_BLOCKS ((B_*S_*HKV_*16) / 256)     // 2048
#define VT_BLOCKS (B_*HKV_*(S_/64))           // 512

// XOR swizzle on LDS byte offsets: key = row bits [9:7] -> flip slot bits [6:4].
// Involution (key bits unchanged by the XOR); spreads 64B-stride rows across all
// 8 16B bank-slots per 128B period: 8-way conflict -> 2-way (free, m136).
#define SWZ(x) ((x) ^ (((x) >> 3) & 0x70))

__device__ __forceinline__ float b2f(u16 x) { return __uint_as_float(((u32)x) << 16); }
__device__ __forceinline__ u16 f2b(float f) {
  u32 u = __float_as_uint(f);
  return (u16)((u + 0x7FFFu + ((u >> 16) & 1u)) >> 16);   // RTNE
}
// dtype probe: cos[0][0]=1.0 -> f32 word 0x3F800000
__device__ __forceinline__ bool is_f32(const void* cs) {
  return ((const u32*)cs)[0] == 0x3F800000u;
}

__device__ __forceinline__ void gload16(const u16* g, u16* l) {
  __builtin_amdgcn_global_load_lds(
      (const __attribute__((address_space(1))) u32*)g,
      (__attribute__((address_space(3))) u32*)l, 16, 0, 0);
}

// ---------------- pre-pass: RoPE(K) -> Kr, transpose(V) -> Vt (both bf16) ----
// K part: 1 thread per 4 rope pairs, 16B loads, fully coalesced.
// V part: per-(b,h,64-row s-block) LDS transpose: coalesced 512B row reads,
//         coalesced 128B Vt row writes (replaces the old 8KB-stride gather /
//         4KB-stride dword scatter).
__global__ __launch_bounds__(256) void rope_pre(
    const void* __restrict__ kin, const void* __restrict__ vin,
    const void* __restrict__ cs, const void* __restrict__ sn, u16* __restrict__ ws)
{
  const bool f32 = is_f32(cs);
  const int bx = blockIdx.x;
  const int t  = threadIdx.x;
  __shared__ u16 tile[64 * 136];   // V transpose tile, pad 136 (8B-aligned rows)

  if (bx < KT_BLOCKS) {
    int tid = bx*256 + t;
    int j4 = tid & 15;                 // d2 = 4*j4 .. +3
    int s  = (tid >> 4) & (S_ - 1);
    int h  = (tid >> 15) & (HKV_ - 1);
    int b  = tid >> 18;
    int gi = ((b*S_ + s)*HKV_ + h)*D_ + 4*j4;
    int ci = s*D_ + 4*j4;
    float xa[4], xb[4], c[4], si[4];
    if (f32) {
      const float* kf = (const float*)kin;
      f32x4 a0 = *(const f32x4*)(kf + gi);
      f32x4 b0 = *(const f32x4*)(kf + gi + 64);
      f32x4 c0 = *(const f32x4*)((const float*)cs + ci);
      f32x4 s0 = *(const f32x4*)((const float*)sn + ci);
#pragma unroll
      for (int e = 0; e < 4; ++e) { xa[e]=a0[e]; xb[e]=b0[e]; c[e]=c0[e]; si[e]=s0[e]; }
    } else {
      const u16* kb16 = (const u16*)kin;
      u16x4 a0 = *(const u16x4*)(kb16 + gi);
      u16x4 b0 = *(const u16x4*)(kb16 + gi + 64);
      u16x4 c0 = *(const u16x4*)((const u16*)cs + ci);
      u16x4 s0 = *(const u16x4*)((const u16*)sn + ci);
#pragma unroll
      for (int e = 0; e < 4; ++e) { xa[e]=b2f(a0[e]); xb[e]=b2f(b0[e]); c[e]=b2f(c0[e]); si[e]=b2f(s0[e]); }
    }
    u16 o0[4], o1[4];
#pragma unroll
    for (int e = 0; e < 4; ++e) {
      o0[e] = f2b(xa[e]*c[e] - xb[e]*si[e]);   // d < 64
      o1[e] = f2b(xb[e]*c[e] + xa[e]*si[e]);   // d >= 64 (cos[d]==cos[d+64])
    }
    int oi = ((b*HKV_ + h)*S_ + s)*D_ + 4*j4;
    *(u16x4*)(ws + oi)      = *(u16x4*)o0;
    *(u16x4*)(ws + oi + 64) = *(u16x4*)o1;
  } else {
    int vb = bx - KT_BLOCKS;           // 0..511
    int sb = vb & 31;                  // 64-row s-block
    int h  = (vb >> 5) & (HKV_ - 1);
    int b  = vb >> 8;
    int s0 = sb * 64;
    // stage: 8 rounds, 1 f32x4 (16B) per thread -> fully coalesced 1KB/instr
#pragma unroll
    for (int it = 0; it < 8; ++it) {
      int task = it*256 + t;           // 2048 = 64 rows x 32 col-groups
      int c4 = task & 31;              // 4 floats
      int r  = task >> 5;
      int gi = ((b*S_ + s0 + r)*HKV_ + h)*D_ + 4*c4;
      u16 e[4];
      if (f32) {
        f32x4 a = *(const f32x4*)((const float*)vin + gi);
#pragma unroll
        for (int j = 0; j < 4; ++j) e[j] = f2b(a[j]);
      } else {
        u16x4 a = *(const u16x4*)((const u16*)vin + gi);
#pragma unroll
        for (int j = 0; j < 4; ++j) e[j] = a[j];
      }
      *(u16x4*)&tile[r*136 + 4*c4] = *(u16x4*)e;
    }
    __syncthreads();
    // write: Vt u32[d][S/2], packed s-pairs; 128B contiguous per 32 lanes
    u32* vtd = (u32*)(ws + KR_ELEMS) + (b*HKV_ + h)*D_*(S_/2);
#pragma unroll
    for (int it = 0; it < 16; ++it) {
      int task = it*256 + t;           // 4096 = 128 d x 32 sp
      int sp = task & 31, d = task >> 5;
      u32 lo = tile[(2*sp)*136 + d];
      u32 hi = tile[(2*sp + 1)*136 + d];
      vtd[d*(S_/2) + s0/2 + sp] = lo | (hi << 16);
    }
  }
}

// ---- flash tile staging: linear LDS dest (gload_lds requirement) + inverse-
// swizzled global source, so swizzled reads see the right data (rule #21).
__device__ __forceinline__ void stage_tile(const u16* __restrict__ Kr,
                                           const u16* __restrict__ Vt,
                                           u16* lds, int bufbyte, int n0, int t) {
#pragma unroll
  for (int it = 0; it < 2; ++it) {     // K tile: logical [c][32 n][32 e] u16 (8KB)
    int a = (t + it*256) * 16;         // linear LDS byte offset
    int l = SWZ(a);                    // logical byte this slot must hold
    gload16(Kr + (n0 + ((l >> 6) & 31))*D_ + (l >> 11)*32 + ((l >> 4) & 3)*8,
            (u16*)((char*)lds + bufbyte + a));
  }
#pragma unroll
  for (int it = 0; it < 2; ++it) {     // V tile: logical [128 d][32 n] u16 (8KB)
    int a = (t + it*256) * 16;
    int l = SWZ(a);
    gload16(Vt + (l >> 6)*S_ + n0 + ((l >> 4) & 3)*8,
            (u16*)((char*)lds + bufbyte + 8192 + a));
  }
}

// ---------------- flash attention, S^T formulation ----------------
// 1024 blocks x 4 waves; block processes Q-tiles {qbp, 31-qbp} (uniform 68
// iters). Wave w owns query rows q0+w*16..+15; query = lane&15 (a COLUMN of
// S^T) so softmax reductions are 2 shuffles. K/V double-buffered with counted
// vmcnt(4): next tile's global_load_lds stay in flight across compute (T3/T4).
__global__ __launch_bounds__(256, 4) void flash_attn(
    const void* __restrict__ qg, const void* __restrict__ cs, const void* __restrict__ sn,
    const u16* __restrict__ ws, float* __restrict__ out)
{
  // LDS bytes: buf0 {K@0, V@8192}, buf1 {K@16384, V@24576}, P^T @32768 (4x1280)
  // Q staging [4][64][32] overlaps buf0 (bytes 0..16383), consumed pre-loop.
  __shared__ __attribute__((aligned(16))) u16 lds[18944];   // 37888 B -> 4 blk/CU

  const bool f32 = is_f32(cs);
  const int t = threadIdx.x;
  const int lane = t & 63, w = t >> 6;
  const int lq = lane & 15, quad = lane >> 4;

  // XCD swizzle: bx%8 = XCD; 2 (b,kvh) combos per XCD (1024 % 8 == 0, bijective)
  int bx = blockIdx.x;
  int g = bx & 7, ii = bx >> 3;
  int combo = g*2 + (ii >> 6);
  int b = combo >> 3, kvh = combo & 7;
  int rr = ii & 63;
  int h   = kvh*4 + (rr & 3);
  int qbp = rr >> 2;

  const u16* Kr = ws + (b*HKV_ + kvh)*S_*D_;
  const u16* Vt = ws + KR_ELEMS + (b*HKV_ + kvh)*D_*S_;

  for (int half = 0; half < 2; ++half) {
    int qb = half ? (31 - qbp) : qbp;
    int q0 = qb * 64;
    if (half) __syncthreads();   // prior inner-loop LDS readers done before Q restage

    // ---- stage Q tile with RoPE applied (swizzled stores) ----
#pragma unroll
    for (int it = 0; it < 2; ++it) {
      int tp = it*256 + t;
      int row = tp >> 3, j = tp & 7;          // 8 threads/row, 16B loads
      int qbase = ((b*S_ + q0 + row)*HQ_ + h)*D_ + 8*j;
      int cbase = (q0 + row)*D_ + 8*j;
      float a[8], bb[8], cc[8], ssv[8];
      if (f32) {
        const float* qf32 = (const float*)qg;
        f32x4 a0 = *(const f32x4*)(qf32 + qbase);
        f32x4 a1 = *(const f32x4*)(qf32 + qbase + 4);
        f32x4 b0 = *(const f32x4*)(qf32 + qbase + 64);
        f32x4 b1 = *(const f32x4*)(qf32 + qbase + 68);
        f32x4 c0 = *(const f32x4*)((const float*)cs + cbase);
        f32x4 c1 = *(const f32x4*)((const float*)cs + cbase + 4);
        f32x4 s0 = *(const f32x4*)((const float*)sn + cbase);
        f32x4 s1 = *(const f32x4*)((const float*)sn + cbase + 4);
#pragma unroll
        for (int e = 0; e < 4; ++e) {
          a[e] = a0[e];  a[4+e] = a1[e];  bb[e] = b0[e]; bb[4+e] = b1[e];
          cc[e] = c0[e]; cc[4+e] = c1[e]; ssv[e] = s0[e]; ssv[4+e] = s1[e];
        }
      } else {
        const u16* qb16 = (const u16*)qg;
        u16x8 xa = *(const u16x8*)(qb16 + qbase);
        u16x8 xb = *(const u16x8*)(qb16 + qbase + 64);
        u16x8 cv = *(const u16x8*)((const u16*)cs + cbase);
        u16x8 sv = *(const u16x8*)((const u16*)sn + cbase);
#pragma unroll
        for (int e = 0; e < 8; ++e) {
          a[e] = b2f(xa[e]); bb[e] = b2f(xb[e]);
          cc[e] = b2f(cv[e]); ssv[e] = b2f(sv[e]);
        }
      }
      u16 o0[8], o1[8];
#pragma unroll
      for (int e = 0; e < 8; ++e) {
        o0[e] = f2b(a[e]*cc[e] - bb[e]*ssv[e]);   // d = 8j+e
        o1[e] = f2b(bb[e]*cc[e] + a[e]*ssv[e]);   // d = 64+8j+e
      }
      int A0 = (j >> 2)*4096 + row*64 + (j & 3)*16;   // logical byte
      int A1 = A0 + 8192;
      *(u16x8*)((char*)lds + SWZ(A0)) = *(u16x8*)o0;
      *(u16x8*)((char*)lds + SWZ(A1)) = *(u16x8*)o1;
    }
    __syncthreads();
    bf16x8 qf[4];
    const int R = w*16 + lq;
#pragma unroll
    for (int c = 0; c < 4; ++c) {
      int L = c*4096 + R*64 + quad*16;
      qf[c] = *(const bf16x8*)((const char*)lds + SWZ(L));
    }
    asm volatile("s_waitcnt lgkmcnt(0)" ::: "memory");   // Q in regs
    __syncthreads();                                     // ...for ALL waves

    f32x4 o[8];
#pragma unroll
    for (int dt = 0; dt < 8; ++dt) o[dt] = (f32x4){0.f, 0.f, 0.f, 0.f};
    float m_i = -1e30f, l_i = 0.f;
    const int qrow = q0 + w*16 + lq;
    const int nkb = 2*qb + 2;              // causal: keys [0, q0+64)

    stage_tile(Kr, Vt, lds, 0, 0, t);      // prologue: tile 0 -> buf0

    for (int kb = 0; kb < nkb; ++kb) {
      const int cur = kb & 1;
      // (A) all waves done reading buf[cur^1] (prev compute) before re-stage
      asm volatile("" ::: "memory");
      __builtin_amdgcn_s_barrier();
      asm volatile("" ::: "memory");
      if (kb + 1 < nkb) {
        stage_tile(Kr, Vt, lds, (cur ^ 1)*16384, (kb + 1)*32, t);
        asm volatile("s_waitcnt vmcnt(4)" ::: "memory");  // tile kb landed; kb+1 in flight
      } else {
        asm volatile("s_waitcnt vmcnt(0)" ::: "memory");
      }
      __builtin_amdgcn_s_barrier();        // (B) tile kb resident for all waves
      asm volatile("" ::: "memory");

      const int n0 = kb * 32;
      const char* kbase = (const char*)lds + cur*16384;
      const char* vbase = kbase + 8192;

      // ---- S^T = K Q^T (two 16-key tiles; rows = keys, cols = queries) ----
      f32x4 sc0 = {0,0,0,0}, sc1 = {0,0,0,0};
#pragma unroll
      for (int c = 0; c < 4; ++c) {
        int L0 = c*2048 + lq*64 + quad*16;
        int L1 = L0 + 1024;                // key row +16
        bf16x8 k0 = *(const bf16x8*)(kbase + SWZ(L0));
        bf16x8 k1 = *(const bf16x8*)(kbase + SWZ(L1));
        sc0 = __builtin_amdgcn_mfma_f32_16x16x32_bf16(k0, qf[c], sc0, 0, 0, 0);
        sc1 = __builtin_amdgcn_mfma_f32_16x16x32_bf16(k1, qf[c], sc1, 0, 0, 0);
      }

      // ---- online softmax: query = column lq -> per-lane scalars ----
      const int kk = n0 + quad*4;
      float s0[4], s1[4];
#pragma unroll
      for (int r = 0; r < 4; ++r) {
        s0[r] = (kk + r      <= qrow) ? sc0[r]*SCALE : -1e30f;
        s1[r] = (kk + 16 + r <= qrow) ? sc1[r]*SCALE : -1e30f;
      }
      float mx = fmaxf(fmaxf(fmaxf(s0[0], s0[1]), fmaxf(s0[2], s0[3])),
                       fmaxf(fmaxf(s1[0], s1[1]), fmaxf(s1[2], s1[3])));
      mx = fmaxf(mx, __shfl_xor(mx, 16));
      mx = fmaxf(mx, __shfl_xor(mx, 32));  // column max across the 4 quads
      // T13 defer-rescale: skip O/l rescale while max growth <= 8 (P <= e^8)
      if (!__all(mx - m_i <= 8.0f)) {
        float mn = fmaxf(m_i, mx);
        float al = __expf(m_i - mn);
        l_i *= al;
#pragma unroll
        for (int dt = 0; dt < 8; ++dt) {
#pragma unroll
          for (int r = 0; r < 4; ++r) o[dt][r] *= al;
        }
        m_i = mn;
      }
      float p0[4], p1[4];
      float rs = 0.f;
#pragma unroll
      for (int r = 0; r < 4; ++r) {
        p0[r] = __expf(s0[r] - m_i);
        p1[r] = __expf(s1[r] - m_i);
        rs += p0[r] + p1[r];
      }
      rs += __shfl_xor(rs, 16);
      rs += __shfl_xor(rs, 32);
      l_i += rs;

      // ---- P^T -> LDS (stride 80B, conflict-free), read back as fragments ----
      u16* pw = &lds[16384 + w*640];
      u16 pk0[4], pk1[4];
#pragma unroll
      for (int r = 0; r < 4; ++r) { pk0[r] = f2b(p0[r]); pk1[r] = f2b(p1[r]); }
      *(uint64_t*)&pw[lq*40 + quad*4]      = *(uint64_t*)pk0;   // tile0 keys
      *(uint64_t*)&pw[lq*40 + 16 + quad*4] = *(uint64_t*)pk1;   // tile1 keys
      asm volatile("s_waitcnt lgkmcnt(0)" ::: "memory");        // intra-wave order
      bf16x8 pf = *(const bf16x8*)&pw[lq*40 + quad*8];          // keys quad*8..+7

      // ---- O^T += V^T P^T ----
#pragma unroll
      for (int dt = 0; dt < 8; ++dt) {
        int Lv = (dt*16 + lq)*64 + quad*16;
        bf16x8 vf = *(const bf16x8*)(vbase + SWZ(Lv));
        o[dt] = __builtin_amdgcn_mfma_f32_16x16x32_bf16(vf, pf, o[dt], 0, 0, 0);
      }
    }

    // ---- epilogue: O^T/l -> out [B][S][HQ][D] f32; 4 consecutive d per lane ----
    float inv = 1.0f / l_i;
    float* op = out + ((b*S_ + qrow)*HQ_ + h)*D_ + quad*4;
#pragma unroll
    for (int dt = 0; dt < 8; ++dt) {
      f32x4 v = { o[dt][0]*inv, o[dt][1]*inv, o[dt][2]*inv, o[dt][3]*inv };
      *(f32x4*)(op + dt*16) = v;
    }
  }
}

extern "C" void kernel_launch(void* const* d_in, const int* in_sizes, int n_in,
                              void* d_out, int out_size, void* d_ws, size_t ws_size,
                              hipStream_t stream) {
  const void* q  = d_in[0];
  const void* k  = d_in[1];
  const void* v  = d_in[2];
  const void* cs = d_in[3];
  const void* sn = d_in[4];
  // d_in[5] (mask) and d_in[6] (scale) are applied analytically in-kernel.
  u16*   ws  = (u16*)d_ws;     // needs 16.8 MB
  float* out = (float*)d_out;  // reference output dtype is float32

  rope_pre<<<KT_BLOCKS + VT_BLOCKS, 256, 0, stream>>>(k, v, cs, sn, ws);   // 2560
  flash_attn<<<B_*HQ_*(S_/128), 256, 0, stream>>>(q, cs, sn, ws, out);     // 1024
}

// Round 4
// 255.008 us; speedup vs baseline: 1.1616x; 1.1104x over previous
//
#include <hip/hip_runtime.h>
#include <stdint.h>

typedef unsigned short u16;
typedef unsigned int   u32;
typedef short bf16x8 __attribute__((ext_vector_type(8)));   // 8 bf16 in 4 VGPRs
typedef u16   u16x8  __attribute__((ext_vector_type(8)));
typedef u16   u16x4  __attribute__((ext_vector_type(4)));
typedef float f32x4  __attribute__((ext_vector_type(4)));

#define B_   2
#define S_   2048
#define HQ_  32
#define HKV_ 8
#define D_   128
// SCALE * log2(e): scores computed directly in log2 domain (exp -> v_exp_f32)
#define SC2  0.1275174457530659f

// workspace (bf16 elems, 16.8 MB): Kr [B][HKV][S][D] roped K; Vt [B][HKV][D][S]
#define KR_ELEMS (B_*HKV_*S_*D_)

#define KT_BLOCKS ((B_*S_*HKV_*16) / 256)     // 2048
#define VT_BLOCKS (B_*HKV_*(S_/64))           // 512

// XOR swizzle on LDS byte offsets: key = row bits [9:7] -> flip slot bits [6:4].
#define SWZ(x) ((x) ^ (((x) >> 3) & 0x70))

__device__ __forceinline__ float b2f(u16 x) { return __uint_as_float(((u32)x) << 16); }
__device__ __forceinline__ u16 f2b(float f) {
  u32 u = __float_as_uint(f);
  return (u16)((u + 0x7FFFu + ((u >> 16) & 1u)) >> 16);   // RTNE
}
__device__ __forceinline__ bool is_f32(const void* cs) {
  return ((const u32*)cs)[0] == 0x3F800000u;   // cos[0][0] == 1.0f
}

#if __has_builtin(__builtin_amdgcn_exp2f)
#define EXP2(x) __builtin_amdgcn_exp2f(x)
#else
#define EXP2(x) exp2f(x)
#endif

// gfx950 dual-dest lane swaps. Builtin returns {new_vdst, new_vsrc}.
// TRUE semantics (ISA; cross-checked vs T12 recipe which only works this way):
//   v_permlane32_swap a,b: a' = [a0,a1,b0,b1], b' = [a2,a3,b2,b3]  (quads)
//   v_permlane16_swap a,b: a' = [a0,b0,a2,b2], b' = [a1,b1,a3,b3]
__device__ __forceinline__ void pl32(u32& a, u32& b) {
  auto r = __builtin_amdgcn_permlane32_swap((int)a, (int)b, false, false);
  a = (u32)r[0]; b = (u32)r[1];
}
__device__ __forceinline__ void pl16(u32& a, u32& b) {
  auto r = __builtin_amdgcn_permlane16_swap((int)a, (int)b, false, false);
  a = (u32)r[0]; b = (u32)r[1];
}
// cross-quad reductions (lanes lq, lq+16, lq+32, lq+48) without ds ops
// (invariant to swap direction/operand order: commutative combine + 2nd stage)
__device__ __forceinline__ float qredmax(float x) {
  u32 a = __float_as_uint(x), b = a;
  pl16(a, b);
  float m = fmaxf(__uint_as_float(a), __uint_as_float(b));
  u32 c = __float_as_uint(m), d = c;
  pl32(c, d);
  return fmaxf(__uint_as_float(c), __uint_as_float(d));
}
__device__ __forceinline__ float qredsum(float x) {
  u32 a = __float_as_uint(x), b = a;
  pl16(a, b);
  float m = __uint_as_float(a) + __uint_as_float(b);
  u32 c = __float_as_uint(m), d = c;
  pl32(c, d);
  return __uint_as_float(c) + __uint_as_float(d);
}
__device__ __forceinline__ u32 cvtpk(float lo, float hi) {
  u32 r;
  asm("v_cvt_pk_bf16_f32 %0, %1, %2" : "=v"(r) : "v"(lo), "v"(hi));
  return r;
}

__device__ __forceinline__ void gload16(const u16* g, u16* l) {
  __builtin_amdgcn_global_load_lds(
      (const __attribute__((address_space(1))) u32*)g,
      (__attribute__((address_space(3))) u32*)l, 16, 0, 0);
}

// ---------------- pre-pass: RoPE(K) -> Kr, transpose(V) -> Vt (both bf16) ----
__global__ __launch_bounds__(256) void rope_pre(
    const void* __restrict__ kin, const void* __restrict__ vin,
    const void* __restrict__ cs, const void* __restrict__ sn, u16* __restrict__ ws)
{
  const bool f32 = is_f32(cs);
  const int bx = blockIdx.x;
  const int t  = threadIdx.x;
  __shared__ u16 tile[64 * 136];   // V transpose tile, pad 136

  if (bx < KT_BLOCKS) {
    int tid = bx*256 + t;
    int j4 = tid & 15;                 // d2 = 4*j4 .. +3
    int s  = (tid >> 4) & (S_ - 1);
    int h  = (tid >> 15) & (HKV_ - 1);
    int b  = tid >> 18;
    int gi = ((b*S_ + s)*HKV_ + h)*D_ + 4*j4;
    int ci = s*D_ + 4*j4;
    float xa[4], xb[4], c[4], si[4];
    if (f32) {
      const float* kf = (const float*)kin;
      f32x4 a0 = *(const f32x4*)(kf + gi);
      f32x4 b0 = *(const f32x4*)(kf + gi + 64);
      f32x4 c0 = *(const f32x4*)((const float*)cs + ci);
      f32x4 s0 = *(const f32x4*)((const float*)sn + ci);
#pragma unroll
      for (int e = 0; e < 4; ++e) { xa[e]=a0[e]; xb[e]=b0[e]; c[e]=c0[e]; si[e]=s0[e]; }
    } else {
      const u16* kb16 = (const u16*)kin;
      u16x4 a0 = *(const u16x4*)(kb16 + gi);
      u16x4 b0 = *(const u16x4*)(kb16 + gi + 64);
      u16x4 c0 = *(const u16x4*)((const u16*)cs + ci);
      u16x4 s0 = *(const u16x4*)((const u16*)sn + ci);
#pragma unroll
      for (int e = 0; e < 4; ++e) { xa[e]=b2f(a0[e]); xb[e]=b2f(b0[e]); c[e]=b2f(c0[e]); si[e]=b2f(s0[e]); }
    }
    u16 o0[4], o1[4];
#pragma unroll
    for (int e = 0; e < 4; ++e) {
      o0[e] = f2b(xa[e]*c[e] - xb[e]*si[e]);   // d < 64
      o1[e] = f2b(xb[e]*c[e] + xa[e]*si[e]);   // d >= 64 (cos[d]==cos[d+64])
    }
    int oi = ((b*HKV_ + h)*S_ + s)*D_ + 4*j4;
    *(u16x4*)(ws + oi)      = *(u16x4*)o0;
    *(u16x4*)(ws + oi + 64) = *(u16x4*)o1;
  } else {
    int vb = bx - KT_BLOCKS;           // 0..511
    int sb = vb & 31;                  // 64-row s-block
    int h  = (vb >> 5) & (HKV_ - 1);
    int b  = vb >> 8;
    int s0 = sb * 64;
#pragma unroll
    for (int it = 0; it < 8; ++it) {
      int task = it*256 + t;           // 2048 = 64 rows x 32 col-groups
      int c4 = task & 31;
      int r  = task >> 5;
      int gi = ((b*S_ + s0 + r)*HKV_ + h)*D_ + 4*c4;
      u16 e[4];
      if (f32) {
        f32x4 a = *(const f32x4*)((const float*)vin + gi);
#pragma unroll
        for (int j = 0; j < 4; ++j) e[j] = f2b(a[j]);
      } else {
        u16x4 a = *(const u16x4*)((const u16*)vin + gi);
#pragma unroll
        for (int j = 0; j < 4; ++j) e[j] = a[j];
      }
      *(u16x4*)&tile[r*136 + 4*c4] = *(u16x4*)e;
    }
    __syncthreads();
    u32* vtd = (u32*)(ws + KR_ELEMS) + (b*HKV_ + h)*D_*(S_/2);
#pragma unroll
    for (int it = 0; it < 16; ++it) {
      int task = it*256 + t;           // 4096 = 128 d x 32 sp
      int sp = task & 31, d = task >> 5;
      u32 lo = tile[(2*sp)*136 + d];
      u32 hi = tile[(2*sp + 1)*136 + d];
      vtd[d*(S_/2) + s0/2 + sp] = lo | (hi << 16);
    }
  }
}

// ---------------- flash attention, S^T formulation ----------------
// 1024 blocks x 4 waves; block processes Q-tiles {qbp, 31-qbp} (uniform 68
// iters). Scores computed pre-scaled in log2 domain (SC2 folded into Q).
// P^T redistributed fully in-register (cvt_pk + permlane swaps); K/V double-
// buffered with counted vmcnt(4).
__global__ __launch_bounds__(256, 4) void flash_attn(
    const void* __restrict__ qg, const void* __restrict__ cs, const void* __restrict__ sn,
    const u16* __restrict__ ws, float* __restrict__ out)
{
  // LDS bytes: buf0 {K@0, V@8192}, buf1 {K@16384, V@24576} = 32768 B total.
  // Q staging [4][64][32] overlaps buf0 (bytes 0..16383), consumed pre-loop.
  __shared__ __attribute__((aligned(16))) u16 lds[16384];
  char* ldsc = (char*)lds;

  const bool f32 = is_f32(cs);
  const int t = threadIdx.x;
  const int lane = t & 63, w = t >> 6;
  const int lq = lane & 15, quad = lane >> 4;

  // One per-lane swizzled offset shared by ALL K/V/Q fragment reads:
  // logical L = (chunkconst) + lq*64 + quad*16, XOR key = (lq>>1)&7 for all.
  const int kq = (lq*64 + quad*16) ^ (((lq >> 1) & 7) << 4);

  // XCD swizzle: bx%8 = XCD; 2 (b,kvh) combos per XCD
  int bx = blockIdx.x;
  int g = bx & 7, ii = bx >> 3;
  int combo = g*2 + (ii >> 6);
  int b = combo >> 3, kvh = combo & 7;
  int rr = ii & 63;
  int h   = kvh*4 + (rr & 3);
  int qbp = rr >> 2;

  const u16* Kr = ws + (b*HKV_ + kvh)*S_*D_;
  const u16* Vt = ws + KR_ELEMS + (b*HKV_ + kvh)*D_*S_;

  // staging sources (linear LDS dest, inverse-swizzled global source — rule #21)
  const int aK0 = t*16, aK1 = t*16 + 4096;
  const int lA0 = SWZ(aK0), lA1 = SWZ(aK1);
  const u16* kg0 = Kr + ((lA0 >> 6) & 31)*D_ + (lA0 >> 11)*32 + ((lA0 >> 4) & 3)*8;
  const u16* kg1 = Kr + ((lA1 >> 6) & 31)*D_ + (lA1 >> 11)*32 + ((lA1 >> 4) & 3)*8;
  const u16* vg0 = Vt + (lA0 >> 6)*S_ + ((lA0 >> 4) & 3)*8;
  const u16* vg1 = Vt + (lA1 >> 6)*S_ + ((lA1 >> 4) & 3)*8;

#define STAGE(bufbyte, n0v) do {                                   \
    gload16(kg0 + (n0v)*D_, (u16*)(ldsc + (bufbyte) + aK0));       \
    gload16(kg1 + (n0v)*D_, (u16*)(ldsc + (bufbyte) + aK1));       \
    gload16(vg0 + (n0v),    (u16*)(ldsc + (bufbyte) + 8192 + aK0));\
    gload16(vg1 + (n0v),    (u16*)(ldsc + (bufbyte) + 8192 + aK1));\
  } while (0)

  for (int half = 0; half < 2; ++half) {
    int qb = half ? (31 - qbp) : qbp;
    int q0 = qb * 64;
    if (half) __syncthreads();   // prior inner-loop LDS readers done before Q restage

    // ---- stage Q tile: RoPE + SC2 scale folded in, swizzled stores ----
#pragma unroll
    for (int it = 0; it < 2; ++it) {
      int tp = it*256 + t;
      int row = tp >> 3, j = tp & 7;          // 8 threads/row, 16B loads
      int qbase = ((b*S_ + q0 + row)*HQ_ + h)*D_ + 8*j;
      int cbase = (q0 + row)*D_ + 8*j;
      float a[8], bb[8], cc[8], ssv[8];
      if (f32) {
        const float* qf32 = (const float*)qg;
        f32x4 a0 = *(const f32x4*)(qf32 + qbase);
        f32x4 a1 = *(const f32x4*)(qf32 + qbase + 4);
        f32x4 b0 = *(const f32x4*)(qf32 + qbase + 64);
        f32x4 b1 = *(const f32x4*)(qf32 + qbase + 68);
        f32x4 c0 = *(const f32x4*)((const float*)cs + cbase);
        f32x4 c1 = *(const f32x4*)((const float*)cs + cbase + 4);
        f32x4 s0 = *(const f32x4*)((const float*)sn + cbase);
        f32x4 s1 = *(const f32x4*)((const float*)sn + cbase + 4);
#pragma unroll
        for (int e = 0; e < 4; ++e) {
          a[e] = a0[e];  a[4+e] = a1[e];  bb[e] = b0[e]; bb[4+e] = b1[e];
          cc[e] = c0[e]; cc[4+e] = c1[e]; ssv[e] = s0[e]; ssv[4+e] = s1[e];
        }
      } else {
        const u16* qb16 = (const u16*)qg;
        u16x8 xa = *(const u16x8*)(qb16 + qbase);
        u16x8 xb = *(const u16x8*)(qb16 + qbase + 64);
        u16x8 cv = *(const u16x8*)((const u16*)cs + cbase);
        u16x8 sv = *(const u16x8*)((const u16*)sn + cbase);
#pragma unroll
        for (int e = 0; e < 8; ++e) {
          a[e] = b2f(xa[e]); bb[e] = b2f(xb[e]);
          cc[e] = b2f(cv[e]); ssv[e] = b2f(sv[e]);
        }
      }
      u16 o0[8], o1[8];
#pragma unroll
      for (int e = 0; e < 8; ++e) {
        float C2 = cc[e]*SC2, S2 = ssv[e]*SC2;
        o0[e] = f2b(a[e]*C2 - bb[e]*S2);    // d = 8j+e   (pre-scaled)
        o1[e] = f2b(bb[e]*C2 + a[e]*S2);    // d = 64+8j+e
      }
      int A0 = (j >> 2)*4096 + row*64 + (j & 3)*16;   // logical byte
      int A1 = A0 + 8192;
      *(u16x8*)(ldsc + SWZ(A0)) = *(u16x8*)o0;
      *(u16x8*)(ldsc + SWZ(A1)) = *(u16x8*)o1;
    }
    __syncthreads();
    bf16x8 qf[4];
#pragma unroll
    for (int c = 0; c < 4; ++c)
      qf[c] = *(const bf16x8*)(ldsc + c*4096 + w*1024 + kq);
    asm volatile("s_waitcnt lgkmcnt(0)" ::: "memory");   // Q in regs
    __syncthreads();                                     // ...for ALL waves

    f32x4 o[8];
#pragma unroll
    for (int dt = 0; dt < 8; ++dt) o[dt] = (f32x4){0.f, 0.f, 0.f, 0.f};
    float m_i = -1e30f, l_i = 0.f;
    const int qrow = q0 + w*16 + lq;
    const int nkb = 2*qb + 2;              // causal: keys [0, q0+64)

    STAGE(0, 0);                           // prologue: tile 0 -> buf0

    for (int kb = 0; kb < nkb; ++kb) {
      const int cur = kb & 1;
      // (A) all waves done reading buf[cur^1] before re-stage
      asm volatile("" ::: "memory");
      __builtin_amdgcn_s_barrier();
      asm volatile("" ::: "memory");
      if (kb + 1 < nkb) {
        STAGE((cur ^ 1) << 14, (kb + 1)*32);
        asm volatile("s_waitcnt vmcnt(4)" ::: "memory");  // tile kb landed
      } else {
        asm volatile("s_waitcnt vmcnt(0)" ::: "memory");
      }
      __builtin_amdgcn_s_barrier();        // (B) tile kb resident for all waves
      asm volatile("" ::: "memory");

      const int n0 = kb * 32;
      const char* tb = ldsc + (cur << 14) + kq;   // single per-iter base

      // ---- S^T = K Q^T (scores arrive pre-scaled, log2 domain) ----
      f32x4 sc0 = {0,0,0,0}, sc1 = {0,0,0,0};
#pragma unroll
      for (int c = 0; c < 4; ++c) {
        bf16x8 k0 = *(const bf16x8*)(tb + c*2048);
        bf16x8 k1 = *(const bf16x8*)(tb + c*2048 + 1024);
        sc0 = __builtin_amdgcn_mfma_f32_16x16x32_bf16(k0, qf[c], sc0, 0, 0, 0);
        sc1 = __builtin_amdgcn_mfma_f32_16x16x32_bf16(k1, qf[c], sc1, 0, 0, 0);
      }

      // ---- online softmax (per-lane scalars; mask only on diagonal tiles) ----
      float s0[4], s1[4];
#pragma unroll
      for (int r = 0; r < 4; ++r) { s0[r] = sc0[r]; s1[r] = sc1[r]; }
      if (kb >= 2*qb) {                    // only last 2 iters cross the diagonal
        const int kk = n0 + quad*4;
#pragma unroll
        for (int r = 0; r < 4; ++r) {
          if (kk + r      > qrow) s0[r] = -1e30f;
          if (kk + 16 + r > qrow) s1[r] = -1e30f;
        }
      }
      float mx = fmaxf(fmaxf(fmaxf(s0[0], s0[1]), fmaxf(s0[2], s0[3])),
                       fmaxf(fmaxf(s1[0], s1[1]), fmaxf(s1[2], s1[3])));
      mx = qredmax(mx);                    // column max across the 4 quads
      // T13 defer-rescale: 11.5 (log2) == 8 nats; P bounded by 2^11.5, f32 O ok
      if (!__all(mx - m_i <= 11.5f)) {
        float mn = fmaxf(m_i, mx);
        float al = EXP2(m_i - mn);
        l_i *= al;
#pragma unroll
        for (int dt = 0; dt < 8; ++dt) {
#pragma unroll
          for (int r = 0; r < 4; ++r) o[dt][r] *= al;
        }
        m_i = mn;
      }
      float p0[4], p1[4];
      float rs = 0.f;
#pragma unroll
      for (int r = 0; r < 4; ++r) {
        p0[r] = EXP2(s0[r] - m_i);
        p1[r] = EXP2(s1[r] - m_i);
        rs += p0[r] + p1[r];
      }
      l_i += qredsum(rs);

      // ---- P^T in-register: cvt_pk pairs + permlane swaps -> B-fragment ----
      // Pair j = keys (2j,2j+1). Across quads: Y0=[p0,p2,p4,p6], Y1=[p1,p3,p5,p7],
      // Z0=[p8,p10,p12,p14], Z1=[p9,p11,p13,p15]. Quad q needs w0..w3 = pairs
      // 4q..4q+3, i.e. w0=[p0,p4,p8,p12], w1=[p1,p5,p9,p13], w2=[p2,p6,p10,p14],
      // w3=[p3,p7,p11,p15].
      // pl32(Y,Z): Y=[p0,p2,p8,p10], Z=[p4,p6,p12,p14]   (a'=[a0,a1,b0,b1])
      // pl16(Y,Z): Y=[p0,p4,p8,p12]=w0, Z=[p2,p6,p10,p14]=w2  (a'=[a0,b0,a2,b2])
      u32 Y0 = cvtpk(p0[0], p0[1]), Y1 = cvtpk(p0[2], p0[3]);
      u32 Z0 = cvtpk(p1[0], p1[1]), Z1 = cvtpk(p1[2], p1[3]);
      pl32(Y0, Z0); pl16(Y0, Z0);          // Y0 = w0, Z0 = w2
      pl32(Y1, Z1); pl16(Y1, Z1);          // Y1 = w1, Z1 = w3
      union { u32 wd[4]; bf16x8 v; } pu;
      pu.wd[0] = Y0; pu.wd[1] = Y1; pu.wd[2] = Z0; pu.wd[3] = Z1;
      bf16x8 pf = pu.v;

      // ---- O^T += V^T P^T ----
#pragma unroll
      for (int dt = 0; dt < 8; ++dt) {
        bf16x8 vf = *(const bf16x8*)(tb + 8192 + dt*1024);
        o[dt] = __builtin_amdgcn_mfma_f32_16x16x32_bf16(vf, pf, o[dt], 0, 0, 0);
      }
    }

    // ---- epilogue: O^T/l -> out [B][S][HQ][D] f32; 4 consecutive d per lane ----
    float inv = 1.0f / l_i;
    float* op = out + ((b*S_ + qrow)*HQ_ + h)*D_ + quad*4;
#pragma unroll
    for (int dt = 0; dt < 8; ++dt) {
      f32x4 v = { o[dt][0]*inv, o[dt][1]*inv, o[dt][2]*inv, o[dt][3]*inv };
      *(f32x4*)(op + dt*16) = v;
    }
  }
#undef STAGE
}

extern "C" void kernel_launch(void* const* d_in, const int* in_sizes, int n_in,
                              void* d_out, int out_size, void* d_ws, size_t ws_size,
                              hipStream_t stream) {
  const void* q  = d_in[0];
  const void* k  = d_in[1];
  const void* v  = d_in[2];
  const void* cs = d_in[3];
  const void* sn = d_in[4];
  // d_in[5] (mask) and d_in[6] (scale) are applied analytically in-kernel.
  u16*   ws  = (u16*)d_ws;     // needs 16.8 MB
  float* out = (float*)d_out;  // reference output dtype is float32

  rope_pre<<<KT_BLOCKS + VT_BLOCKS, 256, 0, stream>>>(k, v, cs, sn, ws);
  flash_attn<<<B_*HQ_*(S_/128), 256, 0, stream>>>(q, cs, sn, ws, out);
}